// Round 12
// baseline (618.999 us; speedup 1.0000x reference)
//
#include <hip/hip_runtime.h>
#include <cstdint>

#define N_NODES 100000
#define N_EDGES 1600000
#define R_REL   5
#define NBASIS  2
#define B_START 512
#define PART_SZ 12500     // 8 * 12500 = 100000 (k_acc swizzle)
#define NBUCK   256
#define BUCK_SZ 391       // 256 * 391 = 100096 >= 100000 (dst buckets)
#define KB_SZ   1954      // 256 * 1954 = 500224 >= 500000 (src*5+et key buckets)
#define EPB     6250      // edges per block in cnt/scat passes
#define STAGE_CAP 7000    // dst-bucket edge count mean 6256, sd ~79

__device__ __forceinline__ unsigned short f2bf(float f) {
    unsigned u = __float_as_uint(f);
    unsigned r = (u + 0x7FFF + ((u >> 16) & 1)) >> 16;  // RNE
    return (unsigned short)r;
}

// pack two bf16 channels from an int (lo/hi) scaled by nv
__device__ __forceinline__ int pack2(int u, float nv) {
    float a = __uint_as_float(((unsigned)u) << 16) * nv;
    float b = __uint_as_float((unsigned)u & 0xFFFF0000u) * nv;
    return (int)f2bf(a) | ((int)f2bf(b) << 16);
}

// ---------------- scatter-free CSR build (dst-sorted) ----------------

// Pass A: per-block 256-dst-bucket histogram (LDS), coalesced table write.
__global__ __launch_bounds__(256) void k_cntb(
    const int* __restrict__ ei, int* __restrict__ bhist) {
    __shared__ int lh[NBUCK];
    int tid = threadIdx.x;
    lh[tid] = 0;
    __syncthreads();
    int base = blockIdx.x * EPB;
    for (int j = tid; j < EPB; j += 256) {
        int dst = ei[N_EDGES + base + j];
        atomicAdd(&lh[dst / BUCK_SZ], 1);
    }
    __syncthreads();
    bhist[blockIdx.x * NBUCK + tid] = lh[tid];
}

// Pass B (generic): scan 256x256 [block][bucket] table in place to
// per-(block,bucket) global bases; bucket bases -> bbase.
__global__ __launch_bounds__(256) void k_scanb(
    int* __restrict__ bhist, int* __restrict__ bbase) {
    int b = threadIdx.x;
    int tot = 0;
    for (int i = 0; i < NBUCK; i += 8) {
        int v0 = bhist[(i + 0) * NBUCK + b], v1 = bhist[(i + 1) * NBUCK + b];
        int v2 = bhist[(i + 2) * NBUCK + b], v3 = bhist[(i + 3) * NBUCK + b];
        int v4 = bhist[(i + 4) * NBUCK + b], v5 = bhist[(i + 5) * NBUCK + b];
        int v6 = bhist[(i + 6) * NBUCK + b], v7 = bhist[(i + 7) * NBUCK + b];
        tot += v0 + v1 + v2 + v3 + v4 + v5 + v6 + v7;
    }
    __shared__ int s[NBUCK];
    s[b] = tot;
    __syncthreads();
    for (int o = 1; o < NBUCK; o <<= 1) {
        int v = (b >= o) ? s[b - o] : 0;
        __syncthreads();
        s[b] += v;
        __syncthreads();
    }
    int base = s[b] - tot;  // exclusive
    bbase[b] = base;
    if (b == NBUCK - 1) bbase[NBUCK] = s[NBUCK - 1];
    int run = base;
    for (int i = 0; i < NBUCK; i += 8) {
        int v0 = bhist[(i + 0) * NBUCK + b], v1 = bhist[(i + 1) * NBUCK + b];
        int v2 = bhist[(i + 2) * NBUCK + b], v3 = bhist[(i + 3) * NBUCK + b];
        int v4 = bhist[(i + 4) * NBUCK + b], v5 = bhist[(i + 5) * NBUCK + b];
        int v6 = bhist[(i + 6) * NBUCK + b], v7 = bhist[(i + 7) * NBUCK + b];
        bhist[(i + 0) * NBUCK + b] = run; run += v0;
        bhist[(i + 1) * NBUCK + b] = run; run += v1;
        bhist[(i + 2) * NBUCK + b] = run; run += v2;
        bhist[(i + 3) * NBUCK + b] = run; run += v3;
        bhist[(i + 4) * NBUCK + b] = run; run += v4;
        bhist[(i + 5) * NBUCK + b] = run; run += v5;
        bhist[(i + 6) * NBUCK + b] = run; run += v6;
        bhist[(i + 7) * NBUCK + b] = run; run += v7;
    }
}

// Pass C: deterministic dst-bucket scatter (run-clustered line-dense writes).
// record = src | et<<17 | dst_local<<20
__global__ __launch_bounds__(256) void k_scat(
    const int* __restrict__ ei, const int* __restrict__ et,
    const int* __restrict__ bhist, int* __restrict__ arena) {
    __shared__ int lc[NBUCK];
    int tid = threadIdx.x;
    lc[tid] = bhist[blockIdx.x * NBUCK + tid];
    __syncthreads();
    int base = blockIdx.x * EPB;
    for (int j = tid; j < EPB; j += 256) {
        int e   = base + j;
        int src = ei[e];
        int dst = ei[N_EDGES + e];
        int t   = et[e];
        int bk  = dst / BUCK_SZ;
        int dl  = dst - bk * BUCK_SZ;
        int pos = atomicAdd(&lc[bk], 1);
        arena[pos] = src | (t << 17) | (dl << 20);
    }
}

// Pass D: one block per dst-bucket; emits dst-sorted streams pk_m, pk_nv and
// CSR offsets off[]. All global writes coalesced.
__global__ __launch_bounds__(256) void k_build(
    const int* __restrict__ arena, const int* __restrict__ bbase,
    int* __restrict__ off, int* __restrict__ pk_m, float* __restrict__ pk_nv) {
    __shared__ int deg5[BUCK_SZ * R_REL];
    __shared__ int loff[BUCK_SZ + 1];
    __shared__ int cur[BUCK_SZ];
    __shared__ int stg[STAGE_CAP];
    int b = blockIdx.x, tid = threadIdx.x;
    int base = bbase[b], end = bbase[b + 1];
    int count = end - base;
    for (int i = tid; i < BUCK_SZ * R_REL; i += 256) deg5[i] = 0;
    __syncthreads();
    for (int i = tid; i < count; i += 256) {
        int r  = arena[base + i];
        int dl = ((unsigned)r) >> 20;
        int t  = (r >> 17) & 7;
        atomicAdd(&deg5[dl * R_REL + t], 1);
    }
    __syncthreads();
    if (tid == 0) {
        int run = 0;
        for (int dl = 0; dl < BUCK_SZ; dl++) {
            loff[dl] = run;
            run += deg5[dl * R_REL + 0] + deg5[dl * R_REL + 1] +
                   deg5[dl * R_REL + 2] + deg5[dl * R_REL + 3] +
                   deg5[dl * R_REL + 4];
        }
        loff[BUCK_SZ] = run;
    }
    __syncthreads();
    for (int dl = tid; dl < BUCK_SZ; dl += 256) {
        int n = b * BUCK_SZ + dl;
        if (n < N_NODES) off[n] = base + loff[dl];
        cur[dl] = loff[dl];
    }
    if (b == NBUCK - 1 && tid == 0) off[N_NODES] = N_EDGES;
    __syncthreads();
    for (int i = tid; i < count; i += 256) {
        int r  = arena[base + i];
        int dl = ((unsigned)r) >> 20;
        int rk = atomicAdd(&cur[dl], 1);
        if (rk < STAGE_CAP) stg[rk] = r;
    }
    __syncthreads();
    for (int i = tid; i < count; i += 256) {
        int r   = stg[i < STAGE_CAP ? i : STAGE_CAP - 1];
        int src = r & 0x1FFFF;
        int t   = (r >> 17) & 7;
        int dl  = ((unsigned)r) >> 20;
        int c   = deg5[dl * R_REL + t];
        pk_m[base + i]  = src | (t << 17);
        pk_nv[base + i] = 1.0f / (float)(c > 0 ? c : 1);
    }
}

// ---------------- src-key grouping (for streaming ySE reads in k_msg) ------

// histogram of key=(src*5+et) buckets over the dst-sorted stream
__global__ __launch_bounds__(256) void k_cnt2(
    const int* __restrict__ pk_m, int* __restrict__ bhist2) {
    __shared__ int lh[NBUCK];
    int tid = threadIdx.x;
    lh[tid] = 0;
    __syncthreads();
    int base = blockIdx.x * EPB;
    for (int j = tid; j < EPB; j += 256) {
        int m = pk_m[base + j];
        int key = (m & 0x1FFFF) * R_REL + ((m >> 17) & 7);
        atomicAdd(&lh[key / KB_SZ], 1);
    }
    __syncthreads();
    bhist2[blockIdx.x * NBUCK + tid] = lh[tid];
}

// scatter {m, nv, dst_slot} into src-key-bucket order
__global__ __launch_bounds__(256) void k_scat2(
    const int* __restrict__ pk_m, const float* __restrict__ pk_nv,
    const int* __restrict__ bhist2, int* __restrict__ se_m,
    float* __restrict__ se_nv, int* __restrict__ se_slot) {
    __shared__ int lc[NBUCK];
    int tid = threadIdx.x;
    lc[tid] = bhist2[blockIdx.x * NBUCK + tid];
    __syncthreads();
    int base = blockIdx.x * EPB;
    for (int j = tid; j < EPB; j += 256) {
        int i = base + j;
        int m = pk_m[i];
        int key = (m & 0x1FFFF) * R_REL + ((m >> 17) & 7);
        int pos = atomicAdd(&lc[key / KB_SZ], 1);
        se_m[pos]    = m;
        se_nv[pos]   = pk_nv[i];
        se_slot[pos] = i;
    }
}

// ---------------- per-layer node transform ---------------------------------
// ySE[n][r][ch] = bf16( comp[r,0]*(h@B0)[ch] + comp[r,1]*(h@B1)[ch] )
// hbase := h@root + bias   (pre-activation base; h holds post-tanh states)

template <int IN>
__global__ __launch_bounds__(256) void k_xform(
    const float* __restrict__ h_in, float* __restrict__ hbase,
    unsigned short* __restrict__ ySE, const float* __restrict__ basis,
    const float* __restrict__ root, const float* __restrict__ biasL,
    const float* __restrict__ compL) {
    int tid  = threadIdx.x;
    int lane = tid & 31;
    int sub  = tid >> 5;
    int g    = blockIdx.x * 8 + sub;   // 1024 blocks * 8 = 8192 groups
    float w0[IN], w1[IN], wr[IN];
#pragma unroll
    for (int i = 0; i < IN; i++) {
        w0[i] = basis[i * 32 + lane];
        w1[i] = basis[IN * 32 + i * 32 + lane];
        wr[i] = root[i * 32 + lane];
    }
    float c0[R_REL], c1[R_REL];
#pragma unroll
    for (int r = 0; r < R_REL; r++) {
        c0[r] = compL[r * NBASIS + 0];
        c1[r] = compL[r * NBASIS + 1];
    }
    float bv = biasL[lane];
    for (int n = g; n < N_NODES; n += 8192) {
        float hn = (lane < IN) ? h_in[n * IN + lane] : 0.f;
        float a0 = 0.f, a1 = 0.f, ar = bv;
#pragma unroll
        for (int i = 0; i < IN; i++) {
            float v = __shfl(hn, i, 32);
            a0 += v * w0[i];
            a1 += v * w1[i];
            ar += v * wr[i];
        }
#pragma unroll
        for (int r = 0; r < R_REL; r++)
            ySE[(size_t)n * (R_REL * 32) + r * 32 + lane] =
                f2bf(c0[r] * a0 + c1[r] * a1);
        hbase[n * 32 + lane] = ar;
    }
}

// ---------------- message pass: random full-line WRITES --------------------
// Edges in src-key-bucket order: ySE reads confined to a ~4MB window per XCD
// span (streaming/L2-hot). msg row = nv * ySE row (bf16, 64B) written to its
// dst-sorted slot: 4-lane dwordx4 teams fully cover each 64B line (no RMW).

__global__ __launch_bounds__(256) void k_msg(
    const unsigned short* __restrict__ ySE, const int* __restrict__ se_m,
    const float* __restrict__ se_nv, const int* __restrict__ se_slot,
    unsigned short* __restrict__ msgb) {
    int p = blockIdx.x & 7, q = blockIdx.x >> 3;
    int L = p * 782 + q;              // XCD p owns a contiguous edge span
    if (L >= N_EDGES / 256) return;
    int tid = threadIdx.x;
    int wv = tid >> 6, ln = tid & 63;
    int idx = L * 256 + wv * 64 + ln;
    int   mL  = se_m[idx];
    float nvL = se_nv[idx];
    int   sL  = se_slot[idx];
    int team = ln >> 2, tl = ln & 3;
    const int4* __restrict__ y4 = (const int4*)ySE;
    int4* __restrict__ mb4 = (int4*)msgb;
#pragma unroll
    for (int r = 0; r < 4; r++) {
        int e = r * 16 + team;
        int m      = __shfl(mL, e, 64);
        float nv   = __shfl(nvL, e, 64);
        int slot   = __shfl(sL, e, 64);
        unsigned key = (unsigned)(m & 0x1FFFF) * R_REL + (unsigned)((m >> 17) & 7);
        int4 v = y4[(size_t)key * 4 + tl];
        int4 o;
        o.x = pack2(v.x, nv);
        o.y = pack2(v.y, nv);
        o.z = pack2(v.z, nv);
        o.w = pack2(v.w, nv);
        mb4[(size_t)slot * 4 + tl] = o;
    }
}

// ---------------- accumulate: fully streaming ------------------------------
// Node-centric; msgs for node n are contiguous [off[n],off[n+1]) 64B rows.
// No gathers, no atomics; single writer per node.

__global__ __launch_bounds__(256) void k_acc(
    const float* __restrict__ hbase, float* __restrict__ h,
    const unsigned short* __restrict__ msgb, const int* __restrict__ off) {
    int tid = threadIdx.x, lane = tid & 31, sub = tid >> 5;
    int part  = blockIdx.x & 7;
    int local = (blockIdx.x >> 3) * 8 + sub;
    if (local >= PART_SZ) return;
    int n = part * PART_SZ + local;
    float acc = hbase[n * 32 + lane];
    int e0 = off[n], e1 = off[n + 1];
    for (int base = e0; base < e1; base += 8) {
        float s = 0.f;
#pragma unroll
        for (int q = 0; q < 8; q++) {
            int e = base + q;
            unsigned short u = (e < e1) ? msgb[(size_t)e * 32 + lane]
                                        : (unsigned short)0;
            s += __uint_as_float((unsigned)u << 16);
        }
        acc += s;
    }
    h[n * 32 + lane] = tanhf(acc);
}

// ---------------- start-node row save + MLP head ----------------

__global__ void k_save(const float* __restrict__ h, const int* __restrict__ start,
                       float* __restrict__ sav) {
    int t = blockIdx.x * blockDim.x + threadIdx.x;
    if (t < B_START * 32) {
        int b = t >> 5, ln = t & 31;
        sav[t] = h[start[b] * 32 + ln];
    }
}

__global__ __launch_bounds__(128) void k_mlp(
    const float* __restrict__ sav, const float* __restrict__ w1,
    const float* __restrict__ b1, const float* __restrict__ w2,
    const float* __restrict__ b2, float* __restrict__ out) {
    __shared__ float cvec[128];
    __shared__ float hb[128];
    __shared__ float lg[8];
    int b = blockIdx.x, t = threadIdx.x;
    cvec[t] = sav[(t >> 5) * (B_START * 32) + b * 32 + (t & 31)];
    __syncthreads();
    float a = b1[t];
#pragma unroll 8
    for (int k = 0; k < 128; k++) a += cvec[k] * w1[k * 128 + t];
    hb[t] = fmaxf(a, 0.f);
    __syncthreads();
    if (t < 5) {
        float a2 = b2[t];
        for (int k = 0; k < 128; k++) a2 += hb[k] * w2[k * 5 + t];
        lg[t] = a2;
    }
    __syncthreads();
    if (t < 5) {
        float m = lg[0];
        for (int j = 1; j < 5; j++) m = fmaxf(m, lg[j]);
        float s = 0.f;
        for (int j = 0; j < 5; j++) s += expf(lg[j] - m);
        out[b * 5 + t] = lg[t] - m - logf(s);
    }
}

// ---------------- launch ----------------

extern "C" void kernel_launch(void* const* d_in, const int* in_sizes, int n_in,
                              void* d_out, int out_size, void* d_ws, size_t ws_size,
                              hipStream_t stream) {
    const float* x      = (const float*)d_in[0];
    const int*   ei     = (const int*)d_in[1];
    const int*   etype  = (const int*)d_in[2];
    const int*   start  = (const int*)d_in[3];
    const float* basis0 = (const float*)d_in[4];
    const float* comp0  = (const float*)d_in[5];
    const float* root0  = (const float*)d_in[6];
    const float* bias0  = (const float*)d_in[7];
    const float* basis  = (const float*)d_in[8];
    const float* comp   = (const float*)d_in[9];
    const float* root   = (const float*)d_in[10];
    const float* bias   = (const float*)d_in[11];
    const float* w1     = (const float*)d_in[12];
    const float* b1     = (const float*)d_in[13];
    const float* w2     = (const float*)d_in[14];
    const float* b2     = (const float*)d_in[15];
    float* out = (float*)d_out;

    char* p = (char*)d_ws;
    auto alloc = [&](size_t bytes) -> void* {
        void* r = (void*)p;
        p += (bytes + 255) & ~(size_t)255;
        return r;
    };
    int*            bhist   = (int*)alloc((size_t)NBUCK * NBUCK * 4);
    int*            bbase   = (int*)alloc((NBUCK + 1) * 4);
    int*            bhist2  = (int*)alloc((size_t)NBUCK * NBUCK * 4);
    int*            bbase2  = (int*)alloc((NBUCK + 1) * 4);
    int*            arena   = (int*)alloc((size_t)N_EDGES * 4);
    int*            off     = (int*)alloc((N_NODES + 1) * 4);
    int*            pk_m    = (int*)alloc((size_t)N_EDGES * 4);
    float*          pk_nv   = (float*)alloc((size_t)N_EDGES * 4);
    int*            se_m    = (int*)alloc((size_t)N_EDGES * 4);
    float*          se_nv   = (float*)alloc((size_t)N_EDGES * 4);
    int*            se_slot = (int*)alloc((size_t)N_EDGES * 4);
    float*          hbase   = (float*)alloc((size_t)N_NODES * 32 * 4);
    float*          h       = (float*)alloc((size_t)N_NODES * 32 * 4);
    unsigned short* ySE     = (unsigned short*)alloc((size_t)N_NODES * R_REL * 32 * 2);
    unsigned short* msgb    = (unsigned short*)alloc((size_t)N_EDGES * 32 * 2);
    float*          sav     = (float*)alloc(4 * B_START * 32 * 4);

    // build: dst-sorted CSR + src-key-grouped edge permutation (once)
    k_cntb<<<NBUCK, 256, 0, stream>>>(ei, bhist);
    k_scanb<<<1, 256, 0, stream>>>(bhist, bbase);
    k_scat<<<NBUCK, 256, 0, stream>>>(ei, etype, bhist, arena);
    k_build<<<NBUCK, 256, 0, stream>>>(arena, bbase, off, pk_m, pk_nv);
    k_cnt2<<<NBUCK, 256, 0, stream>>>(pk_m, bhist2);
    k_scanb<<<1, 256, 0, stream>>>(bhist2, bbase2);
    k_scat2<<<NBUCK, 256, 0, stream>>>(pk_m, pk_nv, bhist2, se_m, se_nv, se_slot);

    int nbMsg = 8 * 782;                   // 6256 blocks
    int nbAcc = 8 * ((PART_SZ + 7) / 8);   // 12504 blocks
    // layer 0 (in=4)
    k_xform<4><<<1024, 256, 0, stream>>>(x, hbase, ySE, basis0, root0, bias0, comp0);
    k_msg<<<nbMsg, 256, 0, stream>>>(ySE, se_m, se_nv, se_slot, msgb);
    k_acc<<<nbAcc, 256, 0, stream>>>(hbase, h, msgb, off);
    k_save<<<64, 256, 0, stream>>>(h, start, sav);
    // layers 1..3 (in=32)
    for (int l = 0; l < 3; l++) {
        k_xform<32><<<1024, 256, 0, stream>>>(h, hbase, ySE,
                                              basis + (size_t)l * 2048,
                                              root + (size_t)l * 1024,
                                              bias + l * 32,
                                              comp + l * 10);
        k_msg<<<nbMsg, 256, 0, stream>>>(ySE, se_m, se_nv, se_slot, msgb);
        k_acc<<<nbAcc, 256, 0, stream>>>(hbase, h, msgb, off);
        k_save<<<64, 256, 0, stream>>>(h, start, sav + (l + 1) * 16384);
    }

    k_mlp<<<B_START, 128, 0, stream>>>(sav, w1, b1, w2, b2, out);
}

// Round 13
// 443.441 us; speedup vs baseline: 1.3959x; 1.3959x over previous
//
#include <hip/hip_runtime.h>
#include <cstdint>

#define N_NODES 100000
#define N_EDGES 1600000
#define R_REL   5
#define NBASIS  2
#define B_START 512
#define PART_SZ 12500     // 8 * 12500 = 100000 (k_edge swizzle)
#define NBUCK   256
#define BUCK_SZ 391       // 256 * 391 = 100096 >= 100000
#define EPB     6250      // edges per block in cnt/scat (256 * 6250 = 1.6M)
#define STAGE_CAP 7000    // bucket edge-count mean 6256, sd ~79

// ---------------- scatter-free CSR build (identical to round 9) ------------

__global__ __launch_bounds__(256) void k_cntb(
    const int* __restrict__ ei, int* __restrict__ bhist) {
    __shared__ int lh[NBUCK];
    int tid = threadIdx.x;
    lh[tid] = 0;
    __syncthreads();
    int base = blockIdx.x * EPB;
    for (int j = tid; j < EPB; j += 256) {
        int dst = ei[N_EDGES + base + j];
        atomicAdd(&lh[dst / BUCK_SZ], 1);
    }
    __syncthreads();
    bhist[blockIdx.x * NBUCK + tid] = lh[tid];
}

__global__ __launch_bounds__(256) void k_scanb(
    int* __restrict__ bhist, int* __restrict__ bbase) {
    int b = threadIdx.x;
    int tot = 0;
    for (int i = 0; i < NBUCK; i += 8) {
        int v0 = bhist[(i + 0) * NBUCK + b], v1 = bhist[(i + 1) * NBUCK + b];
        int v2 = bhist[(i + 2) * NBUCK + b], v3 = bhist[(i + 3) * NBUCK + b];
        int v4 = bhist[(i + 4) * NBUCK + b], v5 = bhist[(i + 5) * NBUCK + b];
        int v6 = bhist[(i + 6) * NBUCK + b], v7 = bhist[(i + 7) * NBUCK + b];
        tot += v0 + v1 + v2 + v3 + v4 + v5 + v6 + v7;
    }
    __shared__ int s[NBUCK];
    s[b] = tot;
    __syncthreads();
    for (int o = 1; o < NBUCK; o <<= 1) {
        int v = (b >= o) ? s[b - o] : 0;
        __syncthreads();
        s[b] += v;
        __syncthreads();
    }
    int base = s[b] - tot;  // exclusive
    bbase[b] = base;
    if (b == NBUCK - 1) bbase[NBUCK] = s[NBUCK - 1];
    int run = base;
    for (int i = 0; i < NBUCK; i += 8) {
        int v0 = bhist[(i + 0) * NBUCK + b], v1 = bhist[(i + 1) * NBUCK + b];
        int v2 = bhist[(i + 2) * NBUCK + b], v3 = bhist[(i + 3) * NBUCK + b];
        int v4 = bhist[(i + 4) * NBUCK + b], v5 = bhist[(i + 5) * NBUCK + b];
        int v6 = bhist[(i + 6) * NBUCK + b], v7 = bhist[(i + 7) * NBUCK + b];
        bhist[(i + 0) * NBUCK + b] = run; run += v0;
        bhist[(i + 1) * NBUCK + b] = run; run += v1;
        bhist[(i + 2) * NBUCK + b] = run; run += v2;
        bhist[(i + 3) * NBUCK + b] = run; run += v3;
        bhist[(i + 4) * NBUCK + b] = run; run += v4;
        bhist[(i + 5) * NBUCK + b] = run; run += v5;
        bhist[(i + 6) * NBUCK + b] = run; run += v6;
        bhist[(i + 7) * NBUCK + b] = run; run += v7;
    }
}

// record = src | et<<17 | dst_local<<20
__global__ __launch_bounds__(256) void k_scat(
    const int* __restrict__ ei, const int* __restrict__ et,
    const int* __restrict__ bhist, int* __restrict__ arena) {
    __shared__ int lc[NBUCK];
    int tid = threadIdx.x;
    lc[tid] = bhist[blockIdx.x * NBUCK + tid];
    __syncthreads();
    int base = blockIdx.x * EPB;
    for (int j = tid; j < EPB; j += 256) {
        int e   = base + j;
        int src = ei[e];
        int dst = ei[N_EDGES + e];
        int t   = et[e];
        int bk  = dst / BUCK_SZ;
        int dl  = dst - bk * BUCK_SZ;
        int pos = atomicAdd(&lc[bk], 1);
        arena[pos] = src | (t << 17) | (dl << 20);
    }
}

__global__ __launch_bounds__(256) void k_build(
    const int* __restrict__ arena, const int* __restrict__ bbase,
    int* __restrict__ off, int* __restrict__ pk_m, float* __restrict__ pk_nv) {
    __shared__ int deg5[BUCK_SZ * R_REL];
    __shared__ int loff[BUCK_SZ + 1];
    __shared__ int cur[BUCK_SZ];
    __shared__ int stg[STAGE_CAP];
    int b = blockIdx.x, tid = threadIdx.x;
    int base = bbase[b], end = bbase[b + 1];
    int count = end - base;
    for (int i = tid; i < BUCK_SZ * R_REL; i += 256) deg5[i] = 0;
    __syncthreads();
    for (int i = tid; i < count; i += 256) {
        int r  = arena[base + i];
        int dl = ((unsigned)r) >> 20;
        int t  = (r >> 17) & 7;
        atomicAdd(&deg5[dl * R_REL + t], 1);
    }
    __syncthreads();
    if (tid == 0) {
        int run = 0;
        for (int dl = 0; dl < BUCK_SZ; dl++) {
            loff[dl] = run;
            run += deg5[dl * R_REL + 0] + deg5[dl * R_REL + 1] +
                   deg5[dl * R_REL + 2] + deg5[dl * R_REL + 3] +
                   deg5[dl * R_REL + 4];
        }
        loff[BUCK_SZ] = run;
    }
    __syncthreads();
    for (int dl = tid; dl < BUCK_SZ; dl += 256) {
        int n = b * BUCK_SZ + dl;
        if (n < N_NODES) off[n] = base + loff[dl];
        cur[dl] = loff[dl];
    }
    if (b == NBUCK - 1 && tid == 0) off[N_NODES] = N_EDGES;
    __syncthreads();
    for (int i = tid; i < count; i += 256) {
        int r  = arena[base + i];
        int dl = ((unsigned)r) >> 20;
        int rk = atomicAdd(&cur[dl], 1);
        if (rk < STAGE_CAP) stg[rk] = r;
    }
    __syncthreads();
    for (int i = tid; i < count; i += 256) {
        int r   = stg[i < STAGE_CAP ? i : STAGE_CAP - 1];
        int src = r & 0x1FFFF;
        int t   = (r >> 17) & 7;
        int dl  = ((unsigned)r) >> 20;
        int c   = deg5[dl * R_REL + t];
        pk_m[base + i]  = src | (t << 17);
        pk_nv[base + i] = 1.0f / (float)(c > 0 ? c : 1);
    }
}

// ---------------- per-layer node transform ---------------------------------
// ypk[n][ch] = uchar2{ int8(y0[ch]/s), int8(y1[ch]/s) },  s = rowmax/127
// sc[n] = s ;  h := h@root + bias  (in-place per-row, race-free)

template <int IN>
__global__ __launch_bounds__(256) void k_xform(
    const float* __restrict__ h_in, float* __restrict__ h_io,
    unsigned short* __restrict__ ypk, float* __restrict__ sc,
    const float* __restrict__ basis, const float* __restrict__ root,
    const float* __restrict__ biasL, const float* __restrict__ compL) {
    (void)compL;
    int tid  = threadIdx.x;
    int lane = tid & 31;
    int sub  = tid >> 5;
    int g    = blockIdx.x * 8 + sub;   // 1024 blocks * 8 = 8192 groups
    float w0[IN], w1[IN], wr[IN];
#pragma unroll
    for (int i = 0; i < IN; i++) {
        w0[i] = basis[i * 32 + lane];
        w1[i] = basis[IN * 32 + i * 32 + lane];
        wr[i] = root[i * 32 + lane];
    }
    float bv = biasL[lane];
    for (int n = g; n < N_NODES; n += 8192) {
        float hn = (lane < IN) ? h_in[n * IN + lane] : 0.f;
        float a0 = 0.f, a1 = 0.f, ar = bv;
#pragma unroll
        for (int i = 0; i < IN; i++) {
            float v = __shfl(hn, i, 32);
            a0 += v * w0[i];
            a1 += v * w1[i];
            ar += v * wr[i];
        }
        // row-wise int8 quantization of (a0,a1) across the 32-lane group
        float mx = fmaxf(fabsf(a0), fabsf(a1));
#pragma unroll
        for (int k = 16; k >= 1; k >>= 1)
            mx = fmaxf(mx, __shfl_xor(mx, k, 32));
        float inv = (mx > 0.f) ? 127.0f / mx : 0.f;
        int q0 = __float2int_rn(a0 * inv);
        int q1 = __float2int_rn(a1 * inv);
        ypk[n * 32 + lane] = (unsigned short)((q0 & 0xFF) | ((q1 & 0xFF) << 8));
        if (lane == 0) sc[n] = mx * (1.0f / 127.0f);
        h_io[n * 32 + lane] = ar;
    }
}

// ---------------- edge aggregation -----------------------------------------
// h[n] = tanh(h[n] + sum_e nv*s[src]*(c0[et]*q0 + c1[et]*q1))
// Table 6.4MB (one 64B line/edge) + 400KB scales: both mostly L2-resident.

__global__ __launch_bounds__(256) void k_edge(
    const unsigned short* __restrict__ ypk, const float* __restrict__ sc,
    float* __restrict__ h, const int* __restrict__ pk_m,
    const float* __restrict__ pk_nv, const int* __restrict__ off,
    const float* __restrict__ compL) {
    __shared__ float Cl[2 * R_REL];
    int tid = threadIdx.x;
    if (tid < 2 * R_REL) Cl[tid] = compL[tid];
    __syncthreads();
    int lane = tid & 31;
    int sub  = tid >> 5;
    int part  = blockIdx.x & 7;
    int local = (blockIdx.x >> 3) * 8 + sub;
    if (local >= PART_SZ) return;
    int n = part * PART_SZ + local;

    float acc = h[n * 32 + lane];
    int e0 = off[n], e1 = off[n + 1];
    for (int base = e0; base < e1; base += 32) {
        int idx = base + lane;
        bool vld = idx < e1;
        int   m  = vld ? pk_m[idx] : 0;
        float nv = vld ? pk_nv[idx] : 0.f;
        int srcL = m & 0x1FFFF;
        int etL  = (m >> 17) & 7;
        float sv = sc[srcL] * nv;            // pad lanes: nv=0 -> cc=0
        float cc0 = sv * Cl[etL * 2];
        float cc1 = sv * Cl[etL * 2 + 1];
        int kmax = e1 - base;
        if (kmax > 32) kmax = 32;
        int kk = (kmax + 7) & ~7;
        for (int j = 0; j < kk; j += 8) {
            int m0 = __shfl(m, j + 0, 32), m1 = __shfl(m, j + 1, 32);
            int m2 = __shfl(m, j + 2, 32), m3 = __shfl(m, j + 3, 32);
            int m4 = __shfl(m, j + 4, 32), m5 = __shfl(m, j + 5, 32);
            int m6 = __shfl(m, j + 6, 32), m7 = __shfl(m, j + 7, 32);
            unsigned short u0 = ypk[(size_t)(m0 & 0x1FFFF) * 32 + lane];
            unsigned short u1 = ypk[(size_t)(m1 & 0x1FFFF) * 32 + lane];
            unsigned short u2 = ypk[(size_t)(m2 & 0x1FFFF) * 32 + lane];
            unsigned short u3 = ypk[(size_t)(m3 & 0x1FFFF) * 32 + lane];
            unsigned short u4 = ypk[(size_t)(m4 & 0x1FFFF) * 32 + lane];
            unsigned short u5 = ypk[(size_t)(m5 & 0x1FFFF) * 32 + lane];
            unsigned short u6 = ypk[(size_t)(m6 & 0x1FFFF) * 32 + lane];
            unsigned short u7 = ypk[(size_t)(m7 & 0x1FFFF) * 32 + lane];
            float x0 = __shfl(cc0, j + 0, 32), z0 = __shfl(cc1, j + 0, 32);
            float x1 = __shfl(cc0, j + 1, 32), z1 = __shfl(cc1, j + 1, 32);
            float x2 = __shfl(cc0, j + 2, 32), z2 = __shfl(cc1, j + 2, 32);
            float x3 = __shfl(cc0, j + 3, 32), z3 = __shfl(cc1, j + 3, 32);
            float x4 = __shfl(cc0, j + 4, 32), z4 = __shfl(cc1, j + 4, 32);
            float x5 = __shfl(cc0, j + 5, 32), z5 = __shfl(cc1, j + 5, 32);
            float x6 = __shfl(cc0, j + 6, 32), z6 = __shfl(cc1, j + 6, 32);
            float x7 = __shfl(cc0, j + 7, 32), z7 = __shfl(cc1, j + 7, 32);
            acc += x0 * (float)(int)(signed char)(u0 & 0xFF)
                 + z0 * (float)(int)(signed char)(u0 >> 8);
            acc += x1 * (float)(int)(signed char)(u1 & 0xFF)
                 + z1 * (float)(int)(signed char)(u1 >> 8);
            acc += x2 * (float)(int)(signed char)(u2 & 0xFF)
                 + z2 * (float)(int)(signed char)(u2 >> 8);
            acc += x3 * (float)(int)(signed char)(u3 & 0xFF)
                 + z3 * (float)(int)(signed char)(u3 >> 8);
            acc += x4 * (float)(int)(signed char)(u4 & 0xFF)
                 + z4 * (float)(int)(signed char)(u4 >> 8);
            acc += x5 * (float)(int)(signed char)(u5 & 0xFF)
                 + z5 * (float)(int)(signed char)(u5 >> 8);
            acc += x6 * (float)(int)(signed char)(u6 & 0xFF)
                 + z6 * (float)(int)(signed char)(u6 >> 8);
            acc += x7 * (float)(int)(signed char)(u7 & 0xFF)
                 + z7 * (float)(int)(signed char)(u7 >> 8);
        }
    }
    h[n * 32 + lane] = tanhf(acc);
}

// ---------------- start-node row save + MLP head ----------------

__global__ void k_save(const float* __restrict__ h, const int* __restrict__ start,
                       float* __restrict__ sav) {
    int t = blockIdx.x * blockDim.x + threadIdx.x;
    if (t < B_START * 32) {
        int b = t >> 5, ln = t & 31;
        sav[t] = h[start[b] * 32 + ln];
    }
}

__global__ __launch_bounds__(128) void k_mlp(
    const float* __restrict__ sav, const float* __restrict__ w1,
    const float* __restrict__ b1, const float* __restrict__ w2,
    const float* __restrict__ b2, float* __restrict__ out) {
    __shared__ float cvec[128];
    __shared__ float hb[128];
    __shared__ float lg[8];
    int b = blockIdx.x, t = threadIdx.x;
    cvec[t] = sav[(t >> 5) * (B_START * 32) + b * 32 + (t & 31)];
    __syncthreads();
    float a = b1[t];
#pragma unroll 8
    for (int k = 0; k < 128; k++) a += cvec[k] * w1[k * 128 + t];
    hb[t] = fmaxf(a, 0.f);
    __syncthreads();
    if (t < 5) {
        float a2 = b2[t];
        for (int k = 0; k < 128; k++) a2 += hb[k] * w2[k * 5 + t];
        lg[t] = a2;
    }
    __syncthreads();
    if (t < 5) {
        float m = lg[0];
        for (int j = 1; j < 5; j++) m = fmaxf(m, lg[j]);
        float s = 0.f;
        for (int j = 0; j < 5; j++) s += expf(lg[j] - m);
        out[b * 5 + t] = lg[t] - m - logf(s);
    }
}

// ---------------- launch ----------------

extern "C" void kernel_launch(void* const* d_in, const int* in_sizes, int n_in,
                              void* d_out, int out_size, void* d_ws, size_t ws_size,
                              hipStream_t stream) {
    const float* x      = (const float*)d_in[0];
    const int*   ei     = (const int*)d_in[1];
    const int*   etype  = (const int*)d_in[2];
    const int*   start  = (const int*)d_in[3];
    const float* basis0 = (const float*)d_in[4];
    const float* comp0  = (const float*)d_in[5];
    const float* root0  = (const float*)d_in[6];
    const float* bias0  = (const float*)d_in[7];
    const float* basis  = (const float*)d_in[8];
    const float* comp   = (const float*)d_in[9];
    const float* root   = (const float*)d_in[10];
    const float* bias   = (const float*)d_in[11];
    const float* w1     = (const float*)d_in[12];
    const float* b1     = (const float*)d_in[13];
    const float* w2     = (const float*)d_in[14];
    const float* b2     = (const float*)d_in[15];
    float* out = (float*)d_out;

    char* p = (char*)d_ws;
    auto alloc = [&](size_t bytes) -> void* {
        void* r = (void*)p;
        p += (bytes + 255) & ~(size_t)255;
        return r;
    };
    int*            bhist = (int*)alloc((size_t)NBUCK * NBUCK * 4);
    int*            bbase = (int*)alloc((NBUCK + 1) * 4);
    int*            arena = (int*)alloc((size_t)N_EDGES * 4);
    int*            off   = (int*)alloc((N_NODES + 1) * 4);
    int*            pk_m  = (int*)alloc((size_t)N_EDGES * 4);
    float*          pk_nv = (float*)alloc((size_t)N_EDGES * 4);
    unsigned short* ypk   = (unsigned short*)alloc((size_t)N_NODES * 32 * 2);
    float*          sc    = (float*)alloc((size_t)N_NODES * 4);
    float*          h     = (float*)alloc((size_t)N_NODES * 32 * 4);
    float*          sav   = (float*)alloc(4 * B_START * 32 * 4);

    k_cntb<<<NBUCK, 256, 0, stream>>>(ei, bhist);
    k_scanb<<<1, 256, 0, stream>>>(bhist, bbase);
    k_scat<<<NBUCK, 256, 0, stream>>>(ei, etype, bhist, arena);
    k_build<<<NBUCK, 256, 0, stream>>>(arena, bbase, off, pk_m, pk_nv);

    int nbEdge = 8 * ((PART_SZ + 7) / 8);  // 12504 blocks
    // layer 0 (in=4)
    k_xform<4><<<1024, 256, 0, stream>>>(x, h, ypk, sc, basis0, root0, bias0, comp0);
    k_edge<<<nbEdge, 256, 0, stream>>>(ypk, sc, h, pk_m, pk_nv, off, comp0);
    k_save<<<64, 256, 0, stream>>>(h, start, sav);
    // layers 1..3 (in=32)
    for (int l = 0; l < 3; l++) {
        k_xform<32><<<1024, 256, 0, stream>>>(h, h, ypk, sc,
                                              basis + (size_t)l * 2048,
                                              root + (size_t)l * 1024,
                                              bias + l * 32,
                                              comp + l * 10);
        k_edge<<<nbEdge, 256, 0, stream>>>(ypk, sc, h, pk_m, pk_nv, off,
                                           comp + l * 10);
        k_save<<<64, 256, 0, stream>>>(h, start, sav + (l + 1) * 16384);
    }

    k_mlp<<<B_START, 128, 0, stream>>>(sav, w1, b1, w2, b2, out);
}

// Round 14
// 398.423 us; speedup vs baseline: 1.5536x; 1.1130x over previous
//
#include <hip/hip_runtime.h>
#include <cstdint>

#define N_NODES 100000
#define N_EDGES 1600000
#define R_REL   5
#define NBASIS  2
#define B_START 512
#define PART_SZ 12500     // 8 * 12500 = 100000 (k_edge swizzle)
#define NBUCK   256
#define BUCK_SZ 391       // 256 * 391 = 100096 >= 100000
#define EPB     6250      // edges per block in cnt/scat (256 * 6250 = 1.6M)
#define STAGE_CAP 7000    // bucket edge-count mean 6256, sd ~79

__device__ __forceinline__ unsigned short f2bf(float f) {
    unsigned u = __float_as_uint(f);
    unsigned r = (u + 0x7FFF + ((u >> 16) & 1)) >> 16;  // RNE
    return (unsigned short)r;
}

// ---------------- scatter-free CSR build (identical to round 9) ------------

__global__ __launch_bounds__(256) void k_cntb(
    const int* __restrict__ ei, int* __restrict__ bhist) {
    __shared__ int lh[NBUCK];
    int tid = threadIdx.x;
    lh[tid] = 0;
    __syncthreads();
    int base = blockIdx.x * EPB;
    for (int j = tid; j < EPB; j += 256) {
        int dst = ei[N_EDGES + base + j];
        atomicAdd(&lh[dst / BUCK_SZ], 1);
    }
    __syncthreads();
    bhist[blockIdx.x * NBUCK + tid] = lh[tid];
}

__global__ __launch_bounds__(256) void k_scanb(
    int* __restrict__ bhist, int* __restrict__ bbase) {
    int b = threadIdx.x;
    int tot = 0;
    for (int i = 0; i < NBUCK; i += 8) {
        int v0 = bhist[(i + 0) * NBUCK + b], v1 = bhist[(i + 1) * NBUCK + b];
        int v2 = bhist[(i + 2) * NBUCK + b], v3 = bhist[(i + 3) * NBUCK + b];
        int v4 = bhist[(i + 4) * NBUCK + b], v5 = bhist[(i + 5) * NBUCK + b];
        int v6 = bhist[(i + 6) * NBUCK + b], v7 = bhist[(i + 7) * NBUCK + b];
        tot += v0 + v1 + v2 + v3 + v4 + v5 + v6 + v7;
    }
    __shared__ int s[NBUCK];
    s[b] = tot;
    __syncthreads();
    for (int o = 1; o < NBUCK; o <<= 1) {
        int v = (b >= o) ? s[b - o] : 0;
        __syncthreads();
        s[b] += v;
        __syncthreads();
    }
    int base = s[b] - tot;  // exclusive
    bbase[b] = base;
    if (b == NBUCK - 1) bbase[NBUCK] = s[NBUCK - 1];
    int run = base;
    for (int i = 0; i < NBUCK; i += 8) {
        int v0 = bhist[(i + 0) * NBUCK + b], v1 = bhist[(i + 1) * NBUCK + b];
        int v2 = bhist[(i + 2) * NBUCK + b], v3 = bhist[(i + 3) * NBUCK + b];
        int v4 = bhist[(i + 4) * NBUCK + b], v5 = bhist[(i + 5) * NBUCK + b];
        int v6 = bhist[(i + 6) * NBUCK + b], v7 = bhist[(i + 7) * NBUCK + b];
        bhist[(i + 0) * NBUCK + b] = run; run += v0;
        bhist[(i + 1) * NBUCK + b] = run; run += v1;
        bhist[(i + 2) * NBUCK + b] = run; run += v2;
        bhist[(i + 3) * NBUCK + b] = run; run += v3;
        bhist[(i + 4) * NBUCK + b] = run; run += v4;
        bhist[(i + 5) * NBUCK + b] = run; run += v5;
        bhist[(i + 6) * NBUCK + b] = run; run += v6;
        bhist[(i + 7) * NBUCK + b] = run; run += v7;
    }
}

// record = src | et<<17 | dst_local<<20
__global__ __launch_bounds__(256) void k_scat(
    const int* __restrict__ ei, const int* __restrict__ et,
    const int* __restrict__ bhist, int* __restrict__ arena) {
    __shared__ int lc[NBUCK];
    int tid = threadIdx.x;
    lc[tid] = bhist[blockIdx.x * NBUCK + tid];
    __syncthreads();
    int base = blockIdx.x * EPB;
    for (int j = tid; j < EPB; j += 256) {
        int e   = base + j;
        int src = ei[e];
        int dst = ei[N_EDGES + e];
        int t   = et[e];
        int bk  = dst / BUCK_SZ;
        int dl  = dst - bk * BUCK_SZ;
        int pos = atomicAdd(&lc[bk], 1);
        arena[pos] = src | (t << 17) | (dl << 20);
    }
}

__global__ __launch_bounds__(256) void k_build(
    const int* __restrict__ arena, const int* __restrict__ bbase,
    int* __restrict__ off, int* __restrict__ pk_m, float* __restrict__ pk_nv) {
    __shared__ int deg5[BUCK_SZ * R_REL];
    __shared__ int loff[BUCK_SZ + 1];
    __shared__ int cur[BUCK_SZ];
    __shared__ int stg[STAGE_CAP];
    int b = blockIdx.x, tid = threadIdx.x;
    int base = bbase[b], end = bbase[b + 1];
    int count = end - base;
    for (int i = tid; i < BUCK_SZ * R_REL; i += 256) deg5[i] = 0;
    __syncthreads();
    for (int i = tid; i < count; i += 256) {
        int r  = arena[base + i];
        int dl = ((unsigned)r) >> 20;
        int t  = (r >> 17) & 7;
        atomicAdd(&deg5[dl * R_REL + t], 1);
    }
    __syncthreads();
    if (tid == 0) {
        int run = 0;
        for (int dl = 0; dl < BUCK_SZ; dl++) {
            loff[dl] = run;
            run += deg5[dl * R_REL + 0] + deg5[dl * R_REL + 1] +
                   deg5[dl * R_REL + 2] + deg5[dl * R_REL + 3] +
                   deg5[dl * R_REL + 4];
        }
        loff[BUCK_SZ] = run;
    }
    __syncthreads();
    for (int dl = tid; dl < BUCK_SZ; dl += 256) {
        int n = b * BUCK_SZ + dl;
        if (n < N_NODES) off[n] = base + loff[dl];
        cur[dl] = loff[dl];
    }
    if (b == NBUCK - 1 && tid == 0) off[N_NODES] = N_EDGES;
    __syncthreads();
    for (int i = tid; i < count; i += 256) {
        int r  = arena[base + i];
        int dl = ((unsigned)r) >> 20;
        int rk = atomicAdd(&cur[dl], 1);
        if (rk < STAGE_CAP) stg[rk] = r;
    }
    __syncthreads();
    for (int i = tid; i < count; i += 256) {
        int r   = stg[i < STAGE_CAP ? i : STAGE_CAP - 1];
        int src = r & 0x1FFFF;
        int t   = (r >> 17) & 7;
        int dl  = ((unsigned)r) >> 20;
        int c   = deg5[dl * R_REL + t];
        pk_m[base + i]  = src | (t << 17);
        pk_nv[base + i] = 1.0f / (float)(c > 0 ? c : 1);
    }
}

// ---------------- per-layer node transform ---------------------------------
// y5[r][n][c] = bf16( comp[r,0]*(h@B0) + comp[r,1]*(h@B1) )   (5 planes)
// h := h@root + bias   (in-place per-row, race-free)

template <int IN>
__global__ __launch_bounds__(256) void k_xform(
    const float* __restrict__ h_in, float* __restrict__ h_io,
    unsigned short* __restrict__ y5, const float* __restrict__ basis,
    const float* __restrict__ root, const float* __restrict__ biasL,
    const float* __restrict__ compL) {
    int tid  = threadIdx.x;
    int lane = tid & 31;
    int sub  = tid >> 5;
    int g    = blockIdx.x * 8 + sub;   // 1024 blocks * 8 = 8192 groups
    float w0[IN], w1[IN], wr[IN];
#pragma unroll
    for (int i = 0; i < IN; i++) {
        w0[i] = basis[i * 32 + lane];
        w1[i] = basis[IN * 32 + i * 32 + lane];
        wr[i] = root[i * 32 + lane];
    }
    float c0[R_REL], c1[R_REL];
#pragma unroll
    for (int r = 0; r < R_REL; r++) {
        c0[r] = compL[r * NBASIS + 0];
        c1[r] = compL[r * NBASIS + 1];
    }
    float bv = biasL[lane];
    for (int n = g; n < N_NODES; n += 8192) {
        float hn = (lane < IN) ? h_in[n * IN + lane] : 0.f;
        float a0 = 0.f, a1 = 0.f, ar = bv;
#pragma unroll
        for (int i = 0; i < IN; i++) {
            float v = __shfl(hn, i, 32);
            a0 += v * w0[i];
            a1 += v * w1[i];
            ar += v * wr[i];
        }
#pragma unroll
        for (int r = 0; r < R_REL; r++)
            y5[(size_t)r * N_NODES * 32 + n * 32 + lane] = f2bf(c0[r] * a0 + c1[r] * a1);
        h_io[n * 32 + lane] = ar;
    }
}

// ---------------- edge aggregation: packed 2-channel gathers ---------------
// Half-wave owns node n. Lanes 0-15 process even edges, 16-31 odd edges;
// lane carries channels (2*hl, 2*hl+1) as one uint load per edge-pair.
// One load instruction fetches 2 edges' rows -> half the issue of round 9.
// Pad lanes: m=0, nv=0 -> row 0 gather times zero (exact).

__global__ __launch_bounds__(256) void k_edge(
    const unsigned short* __restrict__ y5, float* __restrict__ h,
    const int* __restrict__ pk_m, const float* __restrict__ pk_nv,
    const int* __restrict__ off) {
    int tid  = threadIdx.x;
    int lane = tid & 31;
    int sub  = tid >> 5;
    int part  = blockIdx.x & 7;
    int local = (blockIdx.x >> 3) * 8 + sub;
    if (local >= PART_SZ) return;
    int n = part * PART_SZ + local;

    int hl = lane & 15;      // channel-pair index
    int eo = lane >> 4;      // 0: even edges, 1: odd edges
    float acc0 = 0.f, acc1 = 0.f;
    const unsigned* __restrict__ y32 = (const unsigned*)y5;
    int e0 = off[n], e1 = off[n + 1];
    for (int base = e0; base < e1; base += 32) {
        int idx = base + lane;
        bool vld = idx < e1;
        int   m  = vld ? pk_m[idx] : 0;
        float nv = vld ? pk_nv[idx] : 0.f;
        int kmax = e1 - base;
        if (kmax > 32) kmax = 32;
        int kk = (kmax + 15) & ~15;
        for (int j = 0; j < kk; j += 16) {
            unsigned uu[8];
            float    vv[8];
#pragma unroll
            for (int q = 0; q < 8; q++) {
                int es = j + q * 2 + eo;
                int mq = __shfl(m, es, 32);
                vv[q]  = __shfl(nv, es, 32);
                unsigned row = ((unsigned)mq >> 17) * N_NODES + (mq & 0x1FFFF);
                uu[q] = y32[(size_t)row * 16 + hl];
            }
#pragma unroll
            for (int q = 0; q < 8; q++) {
                acc0 += vv[q] * __uint_as_float(uu[q] << 16);
                acc1 += vv[q] * __uint_as_float(uu[q] & 0xFFFF0000u);
            }
        }
    }
    acc0 += __shfl_xor(acc0, 16, 32);
    acc1 += __shfl_xor(acc1, 16, 32);
    if (eo == 0) {
        float2* h2 = (float2*)h;
        float2 hb = h2[(size_t)n * 16 + hl];
        float2 o;
        o.x = tanhf(hb.x + acc0);
        o.y = tanhf(hb.y + acc1);
        h2[(size_t)n * 16 + hl] = o;
    }
}

// ---------------- start-node row save + MLP head ----------------

__global__ void k_save(const float* __restrict__ h, const int* __restrict__ start,
                       float* __restrict__ sav) {
    int t = blockIdx.x * blockDim.x + threadIdx.x;
    if (t < B_START * 32) {
        int b = t >> 5, ln = t & 31;
        sav[t] = h[start[b] * 32 + ln];
    }
}

__global__ __launch_bounds__(128) void k_mlp(
    const float* __restrict__ sav, const float* __restrict__ w1,
    const float* __restrict__ b1, const float* __restrict__ w2,
    const float* __restrict__ b2, float* __restrict__ out) {
    __shared__ float cvec[128];
    __shared__ float hb[128];
    __shared__ float lg[8];
    int b = blockIdx.x, t = threadIdx.x;
    cvec[t] = sav[(t >> 5) * (B_START * 32) + b * 32 + (t & 31)];
    __syncthreads();
    float a = b1[t];
#pragma unroll 8
    for (int k = 0; k < 128; k++) a += cvec[k] * w1[k * 128 + t];
    hb[t] = fmaxf(a, 0.f);
    __syncthreads();
    if (t < 5) {
        float a2 = b2[t];
        for (int k = 0; k < 128; k++) a2 += hb[k] * w2[k * 5 + t];
        lg[t] = a2;
    }
    __syncthreads();
    if (t < 5) {
        float m = lg[0];
        for (int j = 1; j < 5; j++) m = fmaxf(m, lg[j]);
        float s = 0.f;
        for (int j = 0; j < 5; j++) s += expf(lg[j] - m);
        out[b * 5 + t] = lg[t] - m - logf(s);
    }
}

// ---------------- launch ----------------

extern "C" void kernel_launch(void* const* d_in, const int* in_sizes, int n_in,
                              void* d_out, int out_size, void* d_ws, size_t ws_size,
                              hipStream_t stream) {
    const float* x      = (const float*)d_in[0];
    const int*   ei     = (const int*)d_in[1];
    const int*   etype  = (const int*)d_in[2];
    const int*   start  = (const int*)d_in[3];
    const float* basis0 = (const float*)d_in[4];
    const float* comp0  = (const float*)d_in[5];
    const float* root0  = (const float*)d_in[6];
    const float* bias0  = (const float*)d_in[7];
    const float* basis  = (const float*)d_in[8];
    const float* comp   = (const float*)d_in[9];
    const float* root   = (const float*)d_in[10];
    const float* bias   = (const float*)d_in[11];
    const float* w1     = (const float*)d_in[12];
    const float* b1     = (const float*)d_in[13];
    const float* w2     = (const float*)d_in[14];
    const float* b2     = (const float*)d_in[15];
    float* out = (float*)d_out;

    char* p = (char*)d_ws;
    auto alloc = [&](size_t bytes) -> void* {
        void* r = (void*)p;
        p += (bytes + 255) & ~(size_t)255;
        return r;
    };
    int*            bhist = (int*)alloc((size_t)NBUCK * NBUCK * 4);
    int*            bbase = (int*)alloc((NBUCK + 1) * 4);
    int*            arena = (int*)alloc((size_t)N_EDGES * 4);
    int*            off   = (int*)alloc((N_NODES + 1) * 4);
    int*            pk_m  = (int*)alloc((size_t)N_EDGES * 4);
    float*          pk_nv = (float*)alloc((size_t)N_EDGES * 4);
    float*          h     = (float*)alloc((size_t)N_NODES * 32 * 4);
    unsigned short* y5    = (unsigned short*)alloc((size_t)R_REL * N_NODES * 32 * 2);
    float*          sav   = (float*)alloc(4 * B_START * 32 * 4);

    k_cntb<<<NBUCK, 256, 0, stream>>>(ei, bhist);
    k_scanb<<<1, 256, 0, stream>>>(bhist, bbase);
    k_scat<<<NBUCK, 256, 0, stream>>>(ei, etype, bhist, arena);
    k_build<<<NBUCK, 256, 0, stream>>>(arena, bbase, off, pk_m, pk_nv);

    int nbEdge = 8 * ((PART_SZ + 7) / 8);  // 12504 blocks
    // layer 0 (in=4)
    k_xform<4><<<1024, 256, 0, stream>>>(x, h, y5, basis0, root0, bias0, comp0);
    k_edge<<<nbEdge, 256, 0, stream>>>(y5, h, pk_m, pk_nv, off);
    k_save<<<64, 256, 0, stream>>>(h, start, sav);
    // layers 1..3 (in=32)
    for (int l = 0; l < 3; l++) {
        k_xform<32><<<1024, 256, 0, stream>>>(h, h, y5,
                                              basis + (size_t)l * 2048,
                                              root + (size_t)l * 1024,
                                              bias + l * 32,
                                              comp + l * 10);
        k_edge<<<nbEdge, 256, 0, stream>>>(y5, h, pk_m, pk_nv, off);
        k_save<<<64, 256, 0, stream>>>(h, start, sav + (l + 1) * 16384);
    }

    k_mlp<<<B_START, 128, 0, stream>>>(sav, w1, b1, w2, b2, out);
}